// Round 9
// baseline (220.392 us; speedup 1.0000x reference)
//
#include <hip/hip_runtime.h>
#include <hip/hip_fp16.h>
#include <math.h>

#define EPS 1e-12f
#define CAP 48        // padded slots per node; deg ~ Poisson(16), P(>=48) ~ 1e-9
#define NPART 8       // one partition per XCD (blockIdx % 8 -> XCD round-robin)
#define BUCKET_CAP 220000  // expected 200K/bucket, sd ~420 -> +45 sigma headroom

// clang vector types — required by __builtin_nontemporal_load/store
typedef __attribute__((ext_vector_type(4))) _Float16 half4v;
typedef __attribute__((ext_vector_type(8))) _Float16 half8v;   // 16 B row chunk
typedef __attribute__((ext_vector_type(4))) float    float4v;
typedef __attribute__((ext_vector_type(4))) int      int4v;

// ---------------------------------------------------------------------------
// Kernel A.
//  blocks [0, normBlocks): quarter-row norm + NORMALIZED fp16 conversion.
//    feat_hn[row] = fp16(feat[row]/max(||row||,eps)); norm_tbl[row]=max(||row||,eps)
//  blocks [normBlocks, +binBlocks): PHASE-1 BINNING (4096 edges/block).
//    Edges binned by b = dst/partSize into 8 contiguous buckets, entry packed
//    as (src<<14)|dst_local (src<2^17, dst_local<12500<2^14 -> 31 bits).
//    LDS count -> 8 global cursor atomics/block -> dense range writes:
//    write amplification ~1 (vs 79 MB for the direct random scatter, R5-R8).
// ---------------------------------------------------------------------------
__global__ __launch_bounds__(256)
void norm_bin_kernel(const float* __restrict__ feat,
                     float* __restrict__ norm_tbl,
                     _Float16* __restrict__ feat_hn,
                     const int* __restrict__ src,
                     const int* __restrict__ dst,
                     int* __restrict__ gcursor,          // [NPART]
                     unsigned* __restrict__ buckets,     // [NPART*BUCKET_CAP]
                     int nN, int nE, int partSize, int normBlocks) {
    if ((int)blockIdx.x < normBlocks) {
        int wave = (blockIdx.x * 256 + (int)threadIdx.x) >> 6;
        int lane = threadIdx.x & 63;
        int grp  = lane >> 4;
        int l16  = lane & 15;
        int row  = wave * 4 + grp;              // 4 rows per wave
        if (row >= nN) return;
        const float4v* f4 = (const float4v*)feat;
        float4v v = __builtin_nontemporal_load(&f4[(size_t)row * 16 + l16]);
        float s = v.x * v.x + v.y * v.y + v.z * v.z + v.w * v.w;
#pragma unroll
        for (int o = 1; o < 16; o <<= 1)
            s += __shfl_xor(s, o, 64);          // reduce within 16-lane group
        float nrm = fmaxf(sqrtf(s), EPS);
        float r   = 1.0f / nrm;
        if (l16 == 0) norm_tbl[row] = nrm;
        half4v h;
        h.x = (_Float16)(v.x * r); h.y = (_Float16)(v.y * r);
        h.z = (_Float16)(v.z * r); h.w = (_Float16)(v.w * r);
        ((half4v*)feat_hn)[(size_t)row * 16 + l16] = h;
    } else {
        __shared__ int cnt[NPART], gbase[NPART], off[NPART];
        int t = threadIdx.x;
        if (t < NPART) { cnt[t] = 0; off[t] = 0; }
        __syncthreads();

        int bblk = (int)blockIdx.x - normBlocks;
        int e0   = bblk * 4096;

        unsigned packed[16];
        int      bkt[16];
#pragma unroll
        for (int c = 0; c < 4; ++c) {
            int e = e0 + c * 1024 + t * 4;      // coalesced int4 per step
            if (e + 3 < nE) {
                int4v s4 = *(const int4v*)(src + e);
                int4v d4 = *(const int4v*)(dst + e);
                int ss[4] = { s4.x, s4.y, s4.z, s4.w };
                int dd[4] = { d4.x, d4.y, d4.z, d4.w };
#pragma unroll
                for (int j = 0; j < 4; ++j) {
                    int b  = dd[j] / partSize;
                    int dl = dd[j] - b * partSize;
                    packed[c * 4 + j] = ((unsigned)ss[j] << 14) | (unsigned)dl;
                    bkt[c * 4 + j]    = b;
                    atomicAdd(&cnt[b], 1);
                }
            } else {
#pragma unroll
                for (int j = 0; j < 4; ++j) {
                    int ee = e + j;
                    if (ee < nE) {
                        int d  = dst[ee];
                        int b  = d / partSize;
                        int dl = d - b * partSize;
                        packed[c * 4 + j] = ((unsigned)src[ee] << 14) | (unsigned)dl;
                        bkt[c * 4 + j]    = b;
                        atomicAdd(&cnt[b], 1);
                    } else {
                        bkt[c * 4 + j] = -1;
                    }
                }
            }
        }
        __syncthreads();
        if (t < NPART) gbase[t] = atomicAdd(&gcursor[t], cnt[t]);
        __syncthreads();
#pragma unroll
        for (int i = 0; i < 16; ++i) {
            int b = bkt[i];
            if (b >= 0) {
                int p   = atomicAdd(&off[b], 1);
                int idx = gbase[b] + p;
                if (idx < BUCKET_CAP)
                    buckets[(size_t)b * BUCKET_CAP + idx] = packed[i];
            }
        }
    }
}

// ---------------------------------------------------------------------------
// Kernel B: PHASE-2 partition-local scatter.  Partition p = blockIdx & 7 reads
// only its own bucket (~0.8 MB) and scatters into its slot window (2.4 MB) +
// deg window (50 KB) — working set ~3.3 MB, L2-resident on one XCD, so each
// bucket line fills before eviction (one writeback per line, not per store).
// ---------------------------------------------------------------------------
__global__ __launch_bounds__(256)
void scatter_kernel(const unsigned* __restrict__ buckets,
                    const int* __restrict__ gcursor,
                    int* __restrict__ deg,
                    int* __restrict__ slots,
                    int partSize) {
    int p   = blockIdx.x & (NPART - 1);
    int blk = blockIdx.x >> 3;
    int n = gcursor[p];
    if (n > BUCKET_CAP) n = BUCKET_CAP;
    size_t base  = (size_t)p * BUCKET_CAP;
    int    dbase = p * partSize;
    int stride = ((int)gridDim.x >> 3) * 256;
    for (int i = blk * 256 + (int)threadIdx.x; i < n; i += stride) {
        unsigned en = buckets[base + i];
        int s = (int)(en >> 14);
        int d = dbase + (int)(en & 0x3FFFu);
        int sl = atomicAdd(&deg[d], 1);
        if (sl < CAP) slots[(size_t)d * CAP + sl] = s;
    }
}

// ---------------------------------------------------------------------------
// Fused node pass, eighth-row layout: one wave per dst node (unchanged R8).
// lane = grp*8 + l8; lane holds half8 #l8 (16 B); 8 edges per iteration.
// Slot ids + src norms preloaded into lanes (2 gathers/node) and
// __shfl-broadcast — the inner loop's only memory op is the row gather.
// dot(normalized rows) == cos; numerator rescale folds into w = exv*norm_s.
// Constant softmax shift |beta| (|beta*cos| <= |beta|) -> single pass.
// ---------------------------------------------------------------------------
__global__ __launch_bounds__(256)
void agg_kernel(const _Float16* __restrict__ feat_hn,
                const float* __restrict__ norm_tbl,
                const float* __restrict__ beta,
                const int* __restrict__ deg,
                const int* __restrict__ slots,
                float* __restrict__ out, int nN) {
    int node = (blockIdx.x * blockDim.x + threadIdx.x) >> 6;
    int lane = threadIdx.x & 63;
    if (node >= nN) return;
    int grp = lane >> 3;          // 8 groups of 8 lanes
    int l8  = lane & 7;

    const half8v* f8 = (const half8v*)feat_hn;
    half8v hd = f8[(size_t)node * 8 + l8];
    float fd0 = (float)hd.s0, fd1 = (float)hd.s1, fd2 = (float)hd.s2,
          fd3 = (float)hd.s3, fd4 = (float)hd.s4, fd5 = (float)hd.s5,
          fd6 = (float)hd.s6, fd7 = (float)hd.s7;

    float bb    = beta[0];
    float shift = fabsf(bb);

    int n = deg[node];
    if (n > CAP) n = CAP;
    size_t i0 = (size_t)node * CAP;

    int   sl_lane  = (lane < n) ? slots[i0 + lane] : 0;
    float nrm_lane = (lane < n) ? norm_tbl[sl_lane] : 0.0f;

    int nIter = (n + 7) >> 3;

    float a0=0.f,a1=0.f,a2=0.f,a3=0.f,a4=0.f,a5=0.f,a6=0.f,a7=0.f;
    float exsum = 0.f;

    for (int k = 0; k < nIter; ++k) {
        int  idx   = (k << 3) + grp;
        bool valid = (idx < n);
        int   s  = __shfl(sl_lane,  idx, 64);
        float ns = __shfl(nrm_lane, idx, 64);
        half8v hs = f8[(size_t)s * 8 + l8];
        float f0 = (float)hs.s0, f1 = (float)hs.s1, f2 = (float)hs.s2,
              f3 = (float)hs.s3, f4 = (float)hs.s4, f5 = (float)hs.s5,
              f6 = (float)hs.s6, f7 = (float)hs.s7;
        float p = f0*fd0 + f1*fd1 + f2*fd2 + f3*fd3
                + f4*fd4 + f5*fd5 + f6*fd6 + f7*fd7;
#pragma unroll
        for (int o = 1; o < 8; o <<= 1)
            p += __shfl_xor(p, o, 64);          // reduce within 8-lane group
        float exv = valid ? __expf(bb * p - shift) : 0.f;
        exsum += exv;
        float w = exv * ns;                     // rescale to original feat
        a0 += w * f0; a1 += w * f1; a2 += w * f2; a3 += w * f3;
        a4 += w * f4; a5 += w * f5; a6 += w * f6; a7 += w * f7;
    }

#pragma unroll
    for (int o = 8; o < 64; o <<= 1) {          // reduce across the 8 groups
        exsum += __shfl_xor(exsum, o, 64);
        a0 += __shfl_xor(a0, o, 64); a1 += __shfl_xor(a1, o, 64);
        a2 += __shfl_xor(a2, o, 64); a3 += __shfl_xor(a3, o, 64);
        a4 += __shfl_xor(a4, o, 64); a5 += __shfl_xor(a5, o, 64);
        a6 += __shfl_xor(a6, o, 64); a7 += __shfl_xor(a7, o, 64);
    }
    if (grp == 0) {
        float inv = 1.0f / fmaxf(exsum, EPS);
        float4v lo4, hi4;
        lo4.x = a0 * inv; lo4.y = a1 * inv; lo4.z = a2 * inv; lo4.w = a3 * inv;
        hi4.x = a4 * inv; hi4.y = a5 * inv; hi4.z = a6 * inv; hi4.w = a7 * inv;
        float4v* op = (float4v*)(out + (size_t)node * 64 + l8 * 8);
        __builtin_nontemporal_store(lo4, op);
        __builtin_nontemporal_store(hi4, op + 1);
    }
}

// ---------------------------------------------------------------------------
// Workspace:
//   deg[N] | gcursor[8] | norm_tbl[N] | slots[N*CAP] | feat_hn[N*64 fp16]
//   | buckets[8*BUCKET_CAP]
// = 0.4 + 0.4 + 19.2 + 12.8 + 7.0 MB ~ 39.9 MB.  All 16 B-aligned chunks.
// NOTE: packing assumes partSize <= 16384 and nN < 2^17 (holds: N=100000).
// ---------------------------------------------------------------------------
extern "C" void kernel_launch(void* const* d_in, const int* in_sizes, int n_in,
                              void* d_out, int out_size, void* d_ws, size_t ws_size,
                              hipStream_t stream) {
    const float* feat = (const float*)d_in[0];
    const float* beta = (const float*)d_in[1];
    const int*   src  = (const int*)d_in[2];
    const int*   dst  = (const int*)d_in[3];
    int nE = in_sizes[2];
    int nN = in_sizes[0] / 64;
    float* out = (float*)d_out;

    int*      deg      = (int*)d_ws;
    int*      gcursor  = deg + nN;                       // [8]
    float*    norm_tbl = (float*)(gcursor + NPART);
    int*      slots    = (int*)(norm_tbl + nN);
    _Float16* feat_hn  = (_Float16*)(slots + (size_t)nN * CAP);
    unsigned* buckets  = (unsigned*)(feat_hn + (size_t)nN * 64);

    // zero deg + gcursor in one shot (contiguous)
    (void)hipMemsetAsync(deg, 0, ((size_t)nN + NPART) * sizeof(int), stream);

    int partSize = (nN + NPART - 1) / NPART;             // 12500

    int normBlocks = (nN + 15) / 16;                     // 16 rows/block
    int binBlocks  = (nE + 4095) / 4096;                 // 4096 edges/block
    norm_bin_kernel<<<normBlocks + binBlocks, 256, 0, stream>>>(
        feat, norm_tbl, feat_hn, src, dst, gcursor, buckets,
        nN, nE, partSize, normBlocks);

    scatter_kernel<<<1024, 256, 0, stream>>>(buckets, gcursor, deg, slots,
                                             partSize);

    agg_kernel<<<(nN * 64 + 255) / 256, 256, 0, stream>>>(
        feat_hn, norm_tbl, beta, deg, slots, out, nN);
}

// Round 10
// 181.863 us; speedup vs baseline: 1.2119x; 1.2119x over previous
//
#include <hip/hip_runtime.h>
#include <hip/hip_fp16.h>
#include <math.h>

#define EPS 1e-12f
#define CAP 48             // padded slots per node; deg ~ Poisson(16), P(>=48) ~ 1e-9
#define BCAP 2400          // bucket capacity; expected 2046/bucket, sd ~45 (+8 sigma)
#define NBMAX 1024         // LDS counter array bound (NB = ceil(nN/128) = 782)

// clang vector types — required by __builtin_nontemporal_load/store
typedef __attribute__((ext_vector_type(4))) _Float16 half4v;
typedef __attribute__((ext_vector_type(8))) _Float16 half8v;   // 16 B row chunk
typedef __attribute__((ext_vector_type(4))) float    float4v;
typedef __attribute__((ext_vector_type(4))) int      int4v;

// ---------------------------------------------------------------------------
// Kernel A (512 threads).
//  blocks [0, normBlocks): norm + NORMALIZED fp16 conversion (32 rows/block).
//    feat_hn[row] = fp16(feat[row]/max(||row||,eps)); norm_tbl[row] = max(||row||,eps)
//  blocks [normBlocks, ...): bin 16384 edges/block into 128-node buckets.
//    bucket b = dst>>7, entry = (src<<7)|(dst&127)  (24 bits).
//    Two passes over the block's edges (2nd read is L2-hot): LDS count ->
//    per-bucket global reservation -> direct write. ~21 entries/bucket/block
//    => ~1-2 dirty lines per bucket per block (~15 MB total writeback vs
//    63-79 MB for direct slot scatter, R5-R9).
// ---------------------------------------------------------------------------
__global__ __launch_bounds__(512)
void norm_bin_kernel(const float* __restrict__ feat,
                     float* __restrict__ norm_tbl,
                     _Float16* __restrict__ feat_hn,
                     const int* __restrict__ src,
                     const int* __restrict__ dst,
                     int* __restrict__ gcursor,          // [NB]
                     unsigned* __restrict__ buckets,     // [NB*BCAP]
                     int nN, int nE, int normBlocks) {
    if ((int)blockIdx.x < normBlocks) {
        int wave = (blockIdx.x * 512 + (int)threadIdx.x) >> 6;  // global wave id
        int lane = threadIdx.x & 63;
        int grp  = lane >> 4;
        int l16  = lane & 15;
        int row  = wave * 4 + grp;              // 4 rows per wave
        if (row >= nN) return;
        const float4v* f4 = (const float4v*)feat;
        float4v v = __builtin_nontemporal_load(&f4[(size_t)row * 16 + l16]);
        float s = v.x * v.x + v.y * v.y + v.z * v.z + v.w * v.w;
#pragma unroll
        for (int o = 1; o < 16; o <<= 1)
            s += __shfl_xor(s, o, 64);          // reduce within 16-lane group
        float nrm = fmaxf(sqrtf(s), EPS);
        float r   = 1.0f / nrm;
        if (l16 == 0) norm_tbl[row] = nrm;
        half4v h;
        h.x = (_Float16)(v.x * r); h.y = (_Float16)(v.y * r);
        h.z = (_Float16)(v.z * r); h.w = (_Float16)(v.w * r);
        ((half4v*)feat_hn)[(size_t)row * 16 + l16] = h;
    } else {
        __shared__ int cnt[NBMAX], off[NBMAX], gb[NBMAX];
        int NB = (nN + 127) >> 7;
        int t  = threadIdx.x;
        for (int i = t; i < NB; i += 512) { cnt[i] = 0; off[i] = 0; }
        __syncthreads();

        int e0 = ((int)blockIdx.x - normBlocks) * 16384;

        // pass 1: count (dst only)
#pragma unroll
        for (int c = 0; c < 8; ++c) {
            int e = e0 + (c * 512 + t) * 4;
            if (e + 3 < nE) {
                int4v d4 = *(const int4v*)(dst + e);
                atomicAdd(&cnt[d4.x >> 7], 1);
                atomicAdd(&cnt[d4.y >> 7], 1);
                atomicAdd(&cnt[d4.z >> 7], 1);
                atomicAdd(&cnt[d4.w >> 7], 1);
            } else {
                for (int ee = e; ee < nE; ++ee) atomicAdd(&cnt[dst[ee] >> 7], 1);
            }
        }
        __syncthreads();
        for (int i = t; i < NB; i += 512)
            gb[i] = cnt[i] ? atomicAdd(&gcursor[i], cnt[i]) : 0;
        __syncthreads();

        // pass 2: write entries (src+dst; dst re-read is L2-hot)
#pragma unroll
        for (int c = 0; c < 8; ++c) {
            int e = e0 + (c * 512 + t) * 4;
            if (e + 3 < nE) {
                int4v s4 = *(const int4v*)(src + e);
                int4v d4 = *(const int4v*)(dst + e);
                int dd[4] = { d4.x, d4.y, d4.z, d4.w };
                int ss[4] = { s4.x, s4.y, s4.z, s4.w };
#pragma unroll
                for (int j = 0; j < 4; ++j) {
                    int b   = dd[j] >> 7;
                    int idx = gb[b] + atomicAdd(&off[b], 1);
                    if (idx < BCAP)
                        buckets[(size_t)b * BCAP + idx] =
                            ((unsigned)ss[j] << 7) | (unsigned)(dd[j] & 127);
                }
            } else {
                for (int ee = e; ee < nE; ++ee) {
                    int d   = dst[ee];
                    int b   = d >> 7;
                    int idx = gb[b] + atomicAdd(&off[b], 1);
                    if (idx < BCAP)
                        buckets[(size_t)b * BCAP + idx] =
                            ((unsigned)src[ee] << 7) | (unsigned)(d & 127);
                }
            }
        }
    }
}

// ---------------------------------------------------------------------------
// Kernel B: LDS-staged scatter.  One block per 128-node bucket: build
// deg[128] + slots[128*CAP] in LDS (LDS atomics — guaranteed local), then
// flush DENSELY with coalesced int4 stores.  Replaces 63-79 MB of random
// line writebacks with ~20 MB of sequential writes.
// ---------------------------------------------------------------------------
__global__ __launch_bounds__(256)
void scatter_kernel(const unsigned* __restrict__ buckets,
                    const int* __restrict__ gcursor,
                    int* __restrict__ deg_g,
                    int* __restrict__ slots_g,
                    int nN) {
    __shared__ int deg[128];
    __shared__ int slots[128 * CAP];            // 24 KB
    int b    = blockIdx.x;
    int base = b << 7;
    int t    = threadIdx.x;

    if (t < 128) deg[t] = 0;
    __syncthreads();

    int n = gcursor[b];
    if (n > BCAP) n = BCAP;
    size_t bb = (size_t)b * BCAP;
    for (int i = t; i < n; i += 256) {
        unsigned en = buckets[bb + i];
        int dl = (int)(en & 127u);
        int s  = (int)(en >> 7);
        int sl = atomicAdd(&deg[dl], 1);
        if (sl < CAP) slots[dl * CAP + sl] = s;
    }
    __syncthreads();

    if (t < 128) {
        int node = base + t;
        if (node < nN) deg_g[node] = deg[t];
    }
    // flush slots densely (unused/padding lanes contain garbage — agg only
    // reads the first deg entries per node, so that's safe)
    size_t gbase = (size_t)base * CAP;          // divisible by 4
    size_t glim  = (size_t)nN * CAP;
    for (int i = t; i < 128 * CAP / 4; i += 256) {
        size_t gi = gbase + (size_t)i * 4;
        if (gi + 3 < glim) {
            int4v v;
            v.x = slots[i * 4 + 0]; v.y = slots[i * 4 + 1];
            v.z = slots[i * 4 + 2]; v.w = slots[i * 4 + 3];
            *(int4v*)(slots_g + gi) = v;
        }
    }
}

// ---------------------------------------------------------------------------
// Kernel C: fused node pass, eighth-row layout (unchanged from R8 — proven
// 75-80 us).  One wave per dst node; lane = grp*8+l8 holds half8 (16 B);
// 8 edges/iteration; slot ids + src norms preloaded and __shfl-broadcast.
// dot(normalized rows) == cos; w = exv*norm_s; constant shift |beta|.
// ---------------------------------------------------------------------------
__global__ __launch_bounds__(256)
void agg_kernel(const _Float16* __restrict__ feat_hn,
                const float* __restrict__ norm_tbl,
                const float* __restrict__ beta,
                const int* __restrict__ deg,
                const int* __restrict__ slots,
                float* __restrict__ out, int nN) {
    int node = (blockIdx.x * blockDim.x + threadIdx.x) >> 6;
    int lane = threadIdx.x & 63;
    if (node >= nN) return;
    int grp = lane >> 3;          // 8 groups of 8 lanes
    int l8  = lane & 7;

    const half8v* f8 = (const half8v*)feat_hn;
    half8v hd = f8[(size_t)node * 8 + l8];
    float fd0 = (float)hd.s0, fd1 = (float)hd.s1, fd2 = (float)hd.s2,
          fd3 = (float)hd.s3, fd4 = (float)hd.s4, fd5 = (float)hd.s5,
          fd6 = (float)hd.s6, fd7 = (float)hd.s7;

    float bb    = beta[0];
    float shift = fabsf(bb);

    int n = deg[node];
    if (n > CAP) n = CAP;
    size_t i0 = (size_t)node * CAP;

    int   sl_lane  = (lane < n) ? slots[i0 + lane] : 0;
    float nrm_lane = (lane < n) ? norm_tbl[sl_lane] : 0.0f;

    int nIter = (n + 7) >> 3;

    float a0=0.f,a1=0.f,a2=0.f,a3=0.f,a4=0.f,a5=0.f,a6=0.f,a7=0.f;
    float exsum = 0.f;

    for (int k = 0; k < nIter; ++k) {
        int  idx   = (k << 3) + grp;
        bool valid = (idx < n);
        int   s  = __shfl(sl_lane,  idx, 64);
        float ns = __shfl(nrm_lane, idx, 64);
        half8v hs = f8[(size_t)s * 8 + l8];
        float f0 = (float)hs.s0, f1 = (float)hs.s1, f2 = (float)hs.s2,
              f3 = (float)hs.s3, f4 = (float)hs.s4, f5 = (float)hs.s5,
              f6 = (float)hs.s6, f7 = (float)hs.s7;
        float p = f0*fd0 + f1*fd1 + f2*fd2 + f3*fd3
                + f4*fd4 + f5*fd5 + f6*fd6 + f7*fd7;
#pragma unroll
        for (int o = 1; o < 8; o <<= 1)
            p += __shfl_xor(p, o, 64);          // reduce within 8-lane group
        float exv = valid ? __expf(bb * p - shift) : 0.f;
        exsum += exv;
        float w = exv * ns;                     // rescale to original feat
        a0 += w * f0; a1 += w * f1; a2 += w * f2; a3 += w * f3;
        a4 += w * f4; a5 += w * f5; a6 += w * f6; a7 += w * f7;
    }

#pragma unroll
    for (int o = 8; o < 64; o <<= 1) {          // reduce across the 8 groups
        exsum += __shfl_xor(exsum, o, 64);
        a0 += __shfl_xor(a0, o, 64); a1 += __shfl_xor(a1, o, 64);
        a2 += __shfl_xor(a2, o, 64); a3 += __shfl_xor(a3, o, 64);
        a4 += __shfl_xor(a4, o, 64); a5 += __shfl_xor(a5, o, 64);
        a6 += __shfl_xor(a6, o, 64); a7 += __shfl_xor(a7, o, 64);
    }
    if (grp == 0) {
        float inv = 1.0f / fmaxf(exsum, EPS);
        float4v lo4, hi4;
        lo4.x = a0 * inv; lo4.y = a1 * inv; lo4.z = a2 * inv; lo4.w = a3 * inv;
        hi4.x = a4 * inv; hi4.y = a5 * inv; hi4.z = a6 * inv; hi4.w = a7 * inv;
        float4v* op = (float4v*)(out + (size_t)node * 64 + l8 * 8);
        __builtin_nontemporal_store(lo4, op);
        __builtin_nontemporal_store(hi4, op + 1);
    }
}

// ---------------------------------------------------------------------------
// Workspace (ints): gcursor[1024] | norm_tbl[nN] | deg[nN] | slots[nN*CAP]
//                   | feat_hn[nN*64 fp16] | buckets[NB*BCAP]
// ~ 0.004 + 0.4 + 0.4 + 19.2 + 12.8 + 7.5 MB ~ 40.3 MB.
// Packing assumes nN < 2^17 (N=100000 ok).
// ---------------------------------------------------------------------------
extern "C" void kernel_launch(void* const* d_in, const int* in_sizes, int n_in,
                              void* d_out, int out_size, void* d_ws, size_t ws_size,
                              hipStream_t stream) {
    const float* feat = (const float*)d_in[0];
    const float* beta = (const float*)d_in[1];
    const int*   src  = (const int*)d_in[2];
    const int*   dst  = (const int*)d_in[3];
    int nE = in_sizes[2];
    int nN = in_sizes[0] / 64;
    float* out = (float*)d_out;

    int*      gcursor  = (int*)d_ws;                     // [1024]
    float*    norm_tbl = (float*)(gcursor + 1024);
    int*      deg      = (int*)(norm_tbl + nN);
    int*      slots    = deg + nN;
    _Float16* feat_hn  = (_Float16*)(slots + (size_t)nN * CAP);
    unsigned* buckets  = (unsigned*)(feat_hn + (size_t)nN * 64);

    int NB = (nN + 127) >> 7;                            // 782

    (void)hipMemsetAsync(gcursor, 0, 1024 * sizeof(int), stream);

    int normBlocks = (nN + 31) / 32;                     // 32 rows / 512-thr block
    int binBlocks  = (nE + 16383) / 16384;               // 16384 edges / block
    norm_bin_kernel<<<normBlocks + binBlocks, 512, 0, stream>>>(
        feat, norm_tbl, feat_hn, src, dst, gcursor, buckets,
        nN, nE, normBlocks);

    scatter_kernel<<<NB, 256, 0, stream>>>(buckets, gcursor, deg, slots, nN);

    agg_kernel<<<(nN * 64 + 255) / 256, 256, 0, stream>>>(
        feat_hn, norm_tbl, beta, deg, slots, out, nN);
}

// Round 11
// 178.883 us; speedup vs baseline: 1.2320x; 1.0167x over previous
//
#include <hip/hip_runtime.h>
#include <hip/hip_fp16.h>
#include <math.h>

#define EPS 1e-12f
#define CAP 48             // padded slots per node; deg ~ Poisson(16), P(>=48) ~ 1e-9
#define BCAP 2400          // bucket capacity; expected 2046/bucket, sd ~45 (+8 sigma)
#define NBMAX 1024         // LDS counter array bound (NB = ceil(nN/128) = 782)
#define EPB 8192           // edges per bin block

// clang vector types — required by __builtin_nontemporal_load/store
typedef __attribute__((ext_vector_type(4))) _Float16 half4v;
typedef __attribute__((ext_vector_type(8))) _Float16 half8v;   // 16 B row chunk
typedef __attribute__((ext_vector_type(4))) float    float4v;
typedef __attribute__((ext_vector_type(4))) int      int4v;

// ---------------------------------------------------------------------------
// Kernel A (512 threads).
//  blocks [0, normBlocks): norm + NORMALIZED fp16 conversion (32 rows/block).
//  blocks [normBlocks, ...): bin EPB edges/block into 128-node buckets with a
//    BLOCK-LOCAL LDS CSR:  count -> wave-scan exclusive prefix -> LDS-atomic
//    placement into contiguous entries[] -> per-bucket COALESCED BURST flush
//    into globally-reserved contiguous ranges.  This removes the scattered-
//    4B-store wall (R5-R10: ~25M scattered stores/s ceiling); all global
//    writes are now dense runs.  Entry = (src<<7)|(dst&127), 24 bits.
// ---------------------------------------------------------------------------
__global__ __launch_bounds__(512)
void norm_bin_kernel(const float* __restrict__ feat,
                     float* __restrict__ norm_tbl,
                     _Float16* __restrict__ feat_hn,
                     const int* __restrict__ src,
                     const int* __restrict__ dst,
                     int* __restrict__ gcursor,          // [NB]
                     unsigned* __restrict__ buckets,     // [NB*BCAP]
                     int nN, int nE, int normBlocks) {
    if ((int)blockIdx.x < normBlocks) {
        int wave = (blockIdx.x * 512 + (int)threadIdx.x) >> 6;  // global wave id
        int lane = threadIdx.x & 63;
        int grp  = lane >> 4;
        int l16  = lane & 15;
        int row  = wave * 4 + grp;              // 4 rows per wave
        if (row >= nN) return;
        const float4v* f4 = (const float4v*)feat;
        float4v v = __builtin_nontemporal_load(&f4[(size_t)row * 16 + l16]);
        float s = v.x * v.x + v.y * v.y + v.z * v.z + v.w * v.w;
#pragma unroll
        for (int o = 1; o < 16; o <<= 1)
            s += __shfl_xor(s, o, 64);          // reduce within 16-lane group
        float nrm = fmaxf(sqrtf(s), EPS);
        float r   = 1.0f / nrm;
        if (l16 == 0) norm_tbl[row] = nrm;
        half4v h;
        h.x = (_Float16)(v.x * r); h.y = (_Float16)(v.y * r);
        h.z = (_Float16)(v.z * r); h.w = (_Float16)(v.w * r);
        ((half4v*)feat_hn)[(size_t)row * 16 + l16] = h;
    } else {
        __shared__ int      cnt[NBMAX], coff[NBMAX], off[NBMAX], gb[NBMAX];
        __shared__ int      wsum[8];
        __shared__ unsigned entries[EPB];       // 32 KB
        int NB = (nN + 127) >> 7;
        int t  = threadIdx.x;
        for (int i = t; i < NBMAX; i += 512) { cnt[i] = 0; off[i] = 0; }
        __syncthreads();

        int e0 = ((int)blockIdx.x - normBlocks) * EPB;

        // pass 1: count (dst only); EPB/512 = 16 edges/thread via 4x int4
#pragma unroll
        for (int c = 0; c < 4; ++c) {
            int e = e0 + (c * 512 + t) * 4;
            if (e + 3 < nE) {
                int4v d4 = *(const int4v*)(dst + e);
                atomicAdd(&cnt[d4.x >> 7], 1);
                atomicAdd(&cnt[d4.y >> 7], 1);
                atomicAdd(&cnt[d4.z >> 7], 1);
                atomicAdd(&cnt[d4.w >> 7], 1);
            } else {
                for (int ee = e; ee < nE; ++ee) atomicAdd(&cnt[dst[ee] >> 7], 1);
            }
        }
        __syncthreads();

        // exclusive prefix scan of cnt[0..1023] -> coff (2 elems/lane, 8 waves)
        int w = t >> 6, l = t & 63;
        int i0 = w * 128 + l * 2;
        int a  = cnt[i0], b2 = cnt[i0 + 1];
        int s  = a + b2, run = s;
#pragma unroll
        for (int o = 1; o < 64; o <<= 1) {
            int v = __shfl_up(run, o, 64);
            if (l >= o) run += v;
        }
        if (l == 63) wsum[w] = run;
        __syncthreads();
        if (t == 0) {
            int acc = 0;
#pragma unroll
            for (int j = 0; j < 8; ++j) { int v = wsum[j]; wsum[j] = acc; acc += v; }
        }
        __syncthreads();
        int base = wsum[w] + (run - s);
        coff[i0]     = base;
        coff[i0 + 1] = base + a;

        // global range reservation per bucket
        for (int i = t; i < NB; i += 512)
            gb[i] = cnt[i] ? atomicAdd(&gcursor[i], cnt[i]) : 0;
        __syncthreads();

        // pass 2: place entries into block-local CSR (LDS, contiguous/bucket)
#pragma unroll
        for (int c = 0; c < 4; ++c) {
            int e = e0 + (c * 512 + t) * 4;
            if (e + 3 < nE) {
                int4v s4 = *(const int4v*)(src + e);
                int4v d4 = *(const int4v*)(dst + e);
                int dd[4] = { d4.x, d4.y, d4.z, d4.w };
                int ss[4] = { s4.x, s4.y, s4.z, s4.w };
#pragma unroll
                for (int j = 0; j < 4; ++j) {
                    int b = dd[j] >> 7;
                    int p = atomicAdd(&off[b], 1);
                    entries[coff[b] + p] =
                        ((unsigned)ss[j] << 7) | (unsigned)(dd[j] & 127);
                }
            } else {
                for (int ee = e; ee < nE; ++ee) {
                    int d = dst[ee];
                    int b = d >> 7;
                    int p = atomicAdd(&off[b], 1);
                    entries[coff[b] + p] =
                        ((unsigned)src[ee] << 7) | (unsigned)(d & 127);
                }
            }
        }
        __syncthreads();

        // flush: wave w handles buckets w, w+8, ... — lanes write the
        // bucket's contiguous entries to its contiguous global range.
        for (int b = w; b < NB; b += 8) {
            int c = cnt[b];
            if (!c) continue;
            int    gbase = gb[b];
            size_t go    = (size_t)b * BCAP;
            int    lbase = coff[b];
            for (int j = l; j < c; j += 64) {
                int gi = gbase + j;
                if (gi < BCAP) buckets[go + gi] = entries[lbase + j];
            }
        }
    }
}

// ---------------------------------------------------------------------------
// Kernel B: LDS-staged scatter (unchanged R10 — proven fast).  One block per
// 128-node bucket: build deg[128] + slots[128*CAP] in LDS, flush densely.
// ---------------------------------------------------------------------------
__global__ __launch_bounds__(256)
void scatter_kernel(const unsigned* __restrict__ buckets,
                    const int* __restrict__ gcursor,
                    int* __restrict__ deg_g,
                    int* __restrict__ slots_g,
                    int nN) {
    __shared__ int deg[128];
    __shared__ int slots[128 * CAP];            // 24 KB
    int b    = blockIdx.x;
    int base = b << 7;
    int t    = threadIdx.x;

    if (t < 128) deg[t] = 0;
    __syncthreads();

    int n = gcursor[b];
    if (n > BCAP) n = BCAP;
    size_t bb = (size_t)b * BCAP;
    for (int i = t; i < n; i += 256) {
        unsigned en = buckets[bb + i];
        int dl = (int)(en & 127u);
        int s  = (int)(en >> 7);
        int sl = atomicAdd(&deg[dl], 1);
        if (sl < CAP) slots[dl * CAP + sl] = s;
    }
    __syncthreads();

    if (t < 128) {
        int node = base + t;
        if (node < nN) deg_g[node] = deg[t];
    }
    size_t gbase = (size_t)base * CAP;          // divisible by 4
    size_t glim  = (size_t)nN * CAP;
    for (int i = t; i < 128 * CAP / 4; i += 256) {
        size_t gi = gbase + (size_t)i * 4;
        if (gi + 3 < glim) {
            int4v v;
            v.x = slots[i * 4 + 0]; v.y = slots[i * 4 + 1];
            v.z = slots[i * 4 + 2]; v.w = slots[i * 4 + 3];
            *(int4v*)(slots_g + gi) = v;
        }
    }
}

// ---------------------------------------------------------------------------
// Kernel C: fused node pass, eighth-row layout (unchanged R8).  One wave per
// dst node; lane = grp*8+l8 holds half8 (16 B); 8 edges/iteration; slot ids
// + src norms preloaded and __shfl-broadcast.  dot(normalized rows) == cos;
// w = exv*norm_s; constant softmax shift |beta|.
// ---------------------------------------------------------------------------
__global__ __launch_bounds__(256)
void agg_kernel(const _Float16* __restrict__ feat_hn,
                const float* __restrict__ norm_tbl,
                const float* __restrict__ beta,
                const int* __restrict__ deg,
                const int* __restrict__ slots,
                float* __restrict__ out, int nN) {
    int node = (blockIdx.x * blockDim.x + threadIdx.x) >> 6;
    int lane = threadIdx.x & 63;
    if (node >= nN) return;
    int grp = lane >> 3;          // 8 groups of 8 lanes
    int l8  = lane & 7;

    const half8v* f8 = (const half8v*)feat_hn;
    half8v hd = f8[(size_t)node * 8 + l8];
    float fd0 = (float)hd.s0, fd1 = (float)hd.s1, fd2 = (float)hd.s2,
          fd3 = (float)hd.s3, fd4 = (float)hd.s4, fd5 = (float)hd.s5,
          fd6 = (float)hd.s6, fd7 = (float)hd.s7;

    float bb    = beta[0];
    float shift = fabsf(bb);

    int n = deg[node];
    if (n > CAP) n = CAP;
    size_t i0 = (size_t)node * CAP;

    int   sl_lane  = (lane < n) ? slots[i0 + lane] : 0;
    float nrm_lane = (lane < n) ? norm_tbl[sl_lane] : 0.0f;

    int nIter = (n + 7) >> 3;

    float a0=0.f,a1=0.f,a2=0.f,a3=0.f,a4=0.f,a5=0.f,a6=0.f,a7=0.f;
    float exsum = 0.f;

    for (int k = 0; k < nIter; ++k) {
        int  idx   = (k << 3) + grp;
        bool valid = (idx < n);
        int   s  = __shfl(sl_lane,  idx, 64);
        float ns = __shfl(nrm_lane, idx, 64);
        half8v hs = f8[(size_t)s * 8 + l8];
        float f0 = (float)hs.s0, f1 = (float)hs.s1, f2 = (float)hs.s2,
              f3 = (float)hs.s3, f4 = (float)hs.s4, f5 = (float)hs.s5,
              f6 = (float)hs.s6, f7 = (float)hs.s7;
        float p = f0*fd0 + f1*fd1 + f2*fd2 + f3*fd3
                + f4*fd4 + f5*fd5 + f6*fd6 + f7*fd7;
#pragma unroll
        for (int o = 1; o < 8; o <<= 1)
            p += __shfl_xor(p, o, 64);          // reduce within 8-lane group
        float exv = valid ? __expf(bb * p - shift) : 0.f;
        exsum += exv;
        float w = exv * ns;                     // rescale to original feat
        a0 += w * f0; a1 += w * f1; a2 += w * f2; a3 += w * f3;
        a4 += w * f4; a5 += w * f5; a6 += w * f6; a7 += w * f7;
    }

#pragma unroll
    for (int o = 8; o < 64; o <<= 1) {          // reduce across the 8 groups
        exsum += __shfl_xor(exsum, o, 64);
        a0 += __shfl_xor(a0, o, 64); a1 += __shfl_xor(a1, o, 64);
        a2 += __shfl_xor(a2, o, 64); a3 += __shfl_xor(a3, o, 64);
        a4 += __shfl_xor(a4, o, 64); a5 += __shfl_xor(a5, o, 64);
        a6 += __shfl_xor(a6, o, 64); a7 += __shfl_xor(a7, o, 64);
    }
    if (grp == 0) {
        float inv = 1.0f / fmaxf(exsum, EPS);
        float4v lo4, hi4;
        lo4.x = a0 * inv; lo4.y = a1 * inv; lo4.z = a2 * inv; lo4.w = a3 * inv;
        hi4.x = a4 * inv; hi4.y = a5 * inv; hi4.z = a6 * inv; hi4.w = a7 * inv;
        float4v* op = (float4v*)(out + (size_t)node * 64 + l8 * 8);
        __builtin_nontemporal_store(lo4, op);
        __builtin_nontemporal_store(hi4, op + 1);
    }
}

// ---------------------------------------------------------------------------
// Workspace (ints): gcursor[1024] | norm_tbl[nN] | deg[nN] | slots[nN*CAP]
//                   | feat_hn[nN*64 fp16] | buckets[NB*BCAP]
// ~ 40.3 MB.  Packing assumes nN < 2^17 (N=100000 ok).
// ---------------------------------------------------------------------------
extern "C" void kernel_launch(void* const* d_in, const int* in_sizes, int n_in,
                              void* d_out, int out_size, void* d_ws, size_t ws_size,
                              hipStream_t stream) {
    const float* feat = (const float*)d_in[0];
    const float* beta = (const float*)d_in[1];
    const int*   src  = (const int*)d_in[2];
    const int*   dst  = (const int*)d_in[3];
    int nE = in_sizes[2];
    int nN = in_sizes[0] / 64;
    float* out = (float*)d_out;

    int*      gcursor  = (int*)d_ws;                     // [1024]
    float*    norm_tbl = (float*)(gcursor + 1024);
    int*      deg      = (int*)(norm_tbl + nN);
    int*      slots    = deg + nN;
    _Float16* feat_hn  = (_Float16*)(slots + (size_t)nN * CAP);
    unsigned* buckets  = (unsigned*)(feat_hn + (size_t)nN * 64);

    int NB = (nN + 127) >> 7;                            // 782

    (void)hipMemsetAsync(gcursor, 0, 1024 * sizeof(int), stream);

    int normBlocks = (nN + 31) / 32;                     // 32 rows / 512-thr block
    int binBlocks  = (nE + EPB - 1) / EPB;               // 8192 edges / block
    norm_bin_kernel<<<normBlocks + binBlocks, 512, 0, stream>>>(
        feat, norm_tbl, feat_hn, src, dst, gcursor, buckets,
        nN, nE, normBlocks);

    scatter_kernel<<<NB, 256, 0, stream>>>(buckets, gcursor, deg, slots, nN);

    agg_kernel<<<(nN * 64 + 255) / 256, 256, 0, stream>>>(
        feat_hn, norm_tbl, beta, deg, slots, out, nN);
}